// Round 1
// baseline (394.392 us; speedup 1.0000x reference)
//
#include <hip/hip_runtime.h>

#define B_SZ 1024
#define S_SZ 512
#define H_SZ 768
#define K3H  2304   // 3*H
#define HID  512
#define NC   3

// ---------------------------------------------------------------------------
// Kernel 1: three masked-mean pools -> o[b, 3H] (concat order: label 2,3,4)
// One block per batch row. 192 threads; thread t owns float4 column t
// (192 float4 = 768 floats = H). Labels staged in LDS; branch on label is
// block-uniform (same s for all lanes) -> no divergence.
// ---------------------------------------------------------------------------
__global__ __launch_bounds__(192) void pool_kernel(
        const float* __restrict__ emb,   // [B,S,H]
        const int*   __restrict__ men,   // [B,S]
        float*       __restrict__ o)     // [B,3H]
{
    const int b = blockIdx.x;
    const int t = threadIdx.x;

    __shared__ unsigned char lab[S_SZ];
    __shared__ int cnt[3];
    if (t < 3) cnt[t] = 0;
    __syncthreads();

    int c2 = 0, c3 = 0, c4 = 0;
    for (int s = t; s < S_SZ; s += 192) {
        int m = men[b * S_SZ + s];
        lab[s] = (unsigned char)m;
        c2 += (m == 2);
        c3 += (m == 3);
        c4 += (m == 4);
    }
    if (c2) atomicAdd(&cnt[0], c2);
    if (c3) atomicAdd(&cnt[1], c3);
    if (c4) atomicAdd(&cnt[2], c4);
    __syncthreads();

    float4 a2 = {0.f, 0.f, 0.f, 0.f};
    float4 a3 = {0.f, 0.f, 0.f, 0.f};
    float4 a4 = {0.f, 0.f, 0.f, 0.f};

    const float4* base =
        reinterpret_cast<const float4*>(emb + (size_t)b * S_SZ * H_SZ);
    const int row_f4 = H_SZ / 4;  // 192

    #pragma unroll 2
    for (int s = 0; s < S_SZ; ++s) {
        float4 v = base[s * row_f4 + t];
        int m = lab[s];   // block-uniform
        if (m == 2)      { a2.x += v.x; a2.y += v.y; a2.z += v.z; a2.w += v.w; }
        else if (m == 3) { a3.x += v.x; a3.y += v.y; a3.z += v.z; a3.w += v.w; }
        else if (m == 4) { a4.x += v.x; a4.y += v.y; a4.z += v.z; a4.w += v.w; }
    }

    const float f2 = (float)cnt[0];
    const float f3 = (float)cnt[1];
    const float f4 = (float)cnt[2];

    float4* op = reinterpret_cast<float4*>(o + (size_t)b * K3H);
    float4 r2 = {a2.x / f2, a2.y / f2, a2.z / f2, a2.w / f2};
    float4 r3 = {a3.x / f3, a3.y / f3, a3.z / f3, a3.w / f3};
    float4 r4 = {a4.x / f4, a4.y / f4, a4.z / f4, a4.w / f4};
    op[t]           = r2;
    op[192 + t]     = r3;
    op[384 + t]     = r4;
}

// ---------------------------------------------------------------------------
// Kernel 2: h = relu(o @ W1 + b1)   [1024,2304] x [2304,512] -> [1024,512]
// f32 vector-ALU GEMM (no fp32 MFMA on CDNA4). BM=32 BN=64 BK=32, 256
// threads, 2x4 microtile. A-tile stored transposed [BK][BM] padded to 34
// (even pad -> aligned float2 reads, conflict-free writes).
// Grid (8, 32) = 256 blocks -> 1 per CU.
// ---------------------------------------------------------------------------
__global__ __launch_bounds__(256) void mlp1_kernel(
        const float* __restrict__ A,    // o  [1024][2304]
        const float* __restrict__ Bw,   // W1 [2304][512]
        const float* __restrict__ bias, // b1 [512]
        float*       __restrict__ C)    // h  [1024][512]
{
    const int BM = 32, BN = 64, BK = 32;
    __shared__ float As[BK][BM + 2];   // [kk][row], pad 2 keeps float2 aligned
    __shared__ float Bs[BK][BN];       // [kk][col]

    const int t  = threadIdx.x;
    const int m0 = blockIdx.y * BM;
    const int n0 = blockIdx.x * BN;
    const int tr = t / 16;            // 0..15 -> rows tr*2, tr*2+1
    const int tc = t % 16;            // 0..15 -> cols tc*4 .. tc*4+3
    const int ar = t / 32, ac = t % 32;   // A staging
    const int br = t / 64, bc = t % 64;   // B staging

    float acc[2][4] = {{0.f,0.f,0.f,0.f},{0.f,0.f,0.f,0.f}};

    for (int k0 = 0; k0 < K3H; k0 += BK) {
        __syncthreads();
        #pragma unroll
        for (int i = 0; i < 4; ++i)
            As[ac][ar + 8 * i] =
                A[(size_t)(m0 + ar + 8 * i) * K3H + k0 + ac];
        #pragma unroll
        for (int i = 0; i < 8; ++i)
            Bs[br + 4 * i][bc] =
                Bw[(size_t)(k0 + br + 4 * i) * HID + n0 + bc];
        __syncthreads();

        #pragma unroll
        for (int kk = 0; kk < BK; ++kk) {
            float2 av = *reinterpret_cast<const float2*>(&As[kk][tr * 2]);
            float4 bv = *reinterpret_cast<const float4*>(&Bs[kk][tc * 4]);
            acc[0][0] += av.x * bv.x;  acc[0][1] += av.x * bv.y;
            acc[0][2] += av.x * bv.z;  acc[0][3] += av.x * bv.w;
            acc[1][0] += av.y * bv.x;  acc[1][1] += av.y * bv.y;
            acc[1][2] += av.y * bv.z;  acc[1][3] += av.y * bv.w;
        }
    }

    #pragma unroll
    for (int i = 0; i < 2; ++i) {
        #pragma unroll
        for (int j = 0; j < 4; ++j) {
            int m = m0 + tr * 2 + i;
            int n = n0 + tc * 4 + j;
            float v = acc[i][j] + bias[n];
            C[(size_t)m * HID + n] = fmaxf(v, 0.f);
        }
    }
}

// ---------------------------------------------------------------------------
// Kernel 3: out = h @ W2 + b2   [1024,512] x [512,3] -> [1024,3]
// One wave per batch row; shuffle-reduce across 64 lanes.
// ---------------------------------------------------------------------------
__global__ __launch_bounds__(64) void mlp2_kernel(
        const float* __restrict__ h,
        const float* __restrict__ W2,   // [512][3]
        const float* __restrict__ b2,
        float*       __restrict__ out)  // [1024][3]
{
    const int b = blockIdx.x;
    const int l = threadIdx.x;
    float a0 = 0.f, a1 = 0.f, a2 = 0.f;
    for (int k = l; k < HID; k += 64) {
        float hv = h[(size_t)b * HID + k];
        a0 += hv * W2[k * 3 + 0];
        a1 += hv * W2[k * 3 + 1];
        a2 += hv * W2[k * 3 + 2];
    }
    #pragma unroll
    for (int off = 32; off > 0; off >>= 1) {
        a0 += __shfl_down(a0, off);
        a1 += __shfl_down(a1, off);
        a2 += __shfl_down(a2, off);
    }
    if (l == 0) {
        out[b * 3 + 0] = a0 + b2[0];
        out[b * 3 + 1] = a1 + b2[1];
        out[b * 3 + 2] = a2 + b2[2];
    }
}

extern "C" void kernel_launch(void* const* d_in, const int* in_sizes, int n_in,
                              void* d_out, int out_size, void* d_ws, size_t ws_size,
                              hipStream_t stream) {
    const float* emb  = (const float*)d_in[0];
    const int*   men  = (const int*)  d_in[1];
    const float* W1   = (const float*)d_in[2];
    const float* b1   = (const float*)d_in[3];
    const float* W2   = (const float*)d_in[4];
    const float* b2   = (const float*)d_in[5];
    float* out = (float*)d_out;

    float* o = (float*)d_ws;                 // [1024, 2304] f32 = 9.44 MB
    float* h = o + (size_t)B_SZ * K3H;       // [1024, 512]  f32 = 2.10 MB

    pool_kernel<<<B_SZ, 192, 0, stream>>>(emb, men, o);
    mlp1_kernel<<<dim3(HID / 64, B_SZ / 32), 256, 0, stream>>>(o, W1, b1, h);
    mlp2_kernel<<<B_SZ, 64, 0, stream>>>(h, W2, b2, out);
}

// Round 2
// 218.484 us; speedup vs baseline: 1.8051x; 1.8051x over previous
//
#include <hip/hip_runtime.h>
#include <hip/hip_bf16.h>

#define B_SZ 1024
#define S_SZ 512
#define H_SZ 768
#define K3H  2304   // 3*H
#define HID  512
#define NC   3

typedef __attribute__((ext_vector_type(8)))  __bf16        bf16x8;
typedef __attribute__((ext_vector_type(16))) float         f32x16;
typedef __attribute__((ext_vector_type(8)))  unsigned short ushort8x;

__device__ __forceinline__ unsigned short f2bf(float f) {
    unsigned u = __builtin_bit_cast(unsigned, f);
    unsigned r = (u + 0x7fffu + ((u >> 16) & 1u)) >> 16;
    return (unsigned short)r;
}

// ---------------------------------------------------------------------------
// Kernel 1: three masked-mean pools -> o[b, 3H] as bf16 (concat: label 2,3,4)
// One block per batch row, 192 threads (thread t owns float4 column t).
// Wave 0 compacts the ~60% of rows with label in {2,3,4} into an LDS list
// (deterministic ballot/prefix-popcount), so label-0/1 rows are never
// fetched from HBM. Main loop: unroll-4 over the compacted list, 4
// independent float4 loads in flight; tag branches are block-uniform.
// ---------------------------------------------------------------------------
__global__ __launch_bounds__(192) void pool_kernel(
        const float* __restrict__ emb,          // [B,S,H] f32
        const int*   __restrict__ men,          // [B,S]
        unsigned short* __restrict__ o)         // [B,3H] bf16
{
    const int b = blockIdx.x;
    const int t = threadIdx.x;

    __shared__ unsigned short sel[S_SZ];        // s | (tag<<12)
    __shared__ int nsel_sh;
    __shared__ int cnt[3];

    if (t < 64) {
        int basep = 0;
        int c0 = 0, c1 = 0, c2 = 0;
        #pragma unroll
        for (int ch = 0; ch < 8; ++ch) {
            int s = ch * 64 + t;
            int m = men[(size_t)b * S_SZ + s];
            bool pick = (m >= 2);
            unsigned long long mk = __ballot(pick);
            int pos = basep + __popcll(mk & ((1ull << t) - 1ull));
            if (pick) sel[pos] = (unsigned short)(s | ((m - 2) << 12));
            basep += __popcll(mk);
            c0 += (m == 2);
            c1 += (m == 3);
            c2 += (m == 4);
        }
        #pragma unroll
        for (int off = 32; off > 0; off >>= 1) {
            c0 += __shfl_down(c0, off);
            c1 += __shfl_down(c1, off);
            c2 += __shfl_down(c2, off);
        }
        if (t == 0) { nsel_sh = basep; cnt[0] = c0; cnt[1] = c1; cnt[2] = c2; }
    }
    __syncthreads();

    const int ns = nsel_sh;
    float4 a0 = {0.f,0.f,0.f,0.f}, a1 = {0.f,0.f,0.f,0.f}, a2 = {0.f,0.f,0.f,0.f};
    const float4* base =
        reinterpret_cast<const float4*>(emb + (size_t)b * S_SZ * H_SZ);

    #define ACCUM(E, V) do {                                             \
        int tg_ = (E) >> 12;                                             \
        if (tg_ == 0)      { a0.x+=V.x; a0.y+=V.y; a0.z+=V.z; a0.w+=V.w; } \
        else if (tg_ == 1) { a1.x+=V.x; a1.y+=V.y; a1.z+=V.z; a1.w+=V.w; } \
        else               { a2.x+=V.x; a2.y+=V.y; a2.z+=V.z; a2.w+=V.w; } \
    } while (0)

    int i = 0;
    for (; i + 4 <= ns; i += 4) {
        int e0 = sel[i], e1 = sel[i+1], e2 = sel[i+2], e3 = sel[i+3];
        float4 v0 = base[(e0 & 0x1ff) * 192 + t];
        float4 v1 = base[(e1 & 0x1ff) * 192 + t];
        float4 v2 = base[(e2 & 0x1ff) * 192 + t];
        float4 v3 = base[(e3 & 0x1ff) * 192 + t];
        ACCUM(e0, v0); ACCUM(e1, v1); ACCUM(e2, v2); ACCUM(e3, v3);
    }
    for (; i < ns; ++i) {
        int e = sel[i];
        float4 v = base[(e & 0x1ff) * 192 + t];
        ACCUM(e, v);
    }
    #undef ACCUM

    const float r0 = 1.f / (float)cnt[0];
    const float r1 = 1.f / (float)cnt[1];
    const float r2 = 1.f / (float)cnt[2];

    unsigned short* op = o + (size_t)b * K3H;
    ushort4 w0 = { f2bf(a0.x*r0), f2bf(a0.y*r0), f2bf(a0.z*r0), f2bf(a0.w*r0) };
    ushort4 w1 = { f2bf(a1.x*r1), f2bf(a1.y*r1), f2bf(a1.z*r1), f2bf(a1.w*r1) };
    ushort4 w2 = { f2bf(a2.x*r2), f2bf(a2.y*r2), f2bf(a2.z*r2), f2bf(a2.w*r2) };
    *reinterpret_cast<ushort4*>(op + 0 * H_SZ + t * 4) = w0;
    *reinterpret_cast<ushort4*>(op + 1 * H_SZ + t * 4) = w1;
    *reinterpret_cast<ushort4*>(op + 2 * H_SZ + t * 4) = w2;
}

// ---------------------------------------------------------------------------
// Kernel 2: W1 [2304][512] f32  ->  W1T [512][2304] bf16  (32x32 LDS tiles)
// ---------------------------------------------------------------------------
__global__ __launch_bounds__(256) void transpose_kernel(
        const float* __restrict__ W1, unsigned short* __restrict__ Bt)
{
    __shared__ unsigned short tile[32][33];
    const int kb = blockIdx.x * 32, nb = blockIdx.y * 32;
    const int c = threadIdx.x & 31, r0 = threadIdx.x >> 5;
    #pragma unroll
    for (int i = 0; i < 4; ++i) {
        int r = r0 + i * 8;
        tile[r][c] = f2bf(W1[(size_t)(kb + r) * HID + nb + c]);
    }
    __syncthreads();
    #pragma unroll
    for (int i = 0; i < 4; ++i) {
        int r = r0 + i * 8;
        Bt[(size_t)(nb + r) * K3H + kb + c] = tile[c][r];
    }
}

// ---------------------------------------------------------------------------
// Kernel 3: h = relu(o @ W1 + b1) via bf16 MFMA, f32 accumulate.
// A = o bf16 [1024][2304] (k-contiguous), B = W1T bf16 [512][2304]
// (k-contiguous). 64x64 block tile, BK=64, 4 waves (2x2), each wave one
// 32x32 quadrant via mfma_f32_32x32x16_bf16. LDS rows padded to 72 bf16
// (144 B, 16B-aligned) -> conflict-free ds_read_b128 / ds_write_b128.
// Grid (8,16) = 128 blocks.
// ---------------------------------------------------------------------------
__global__ __launch_bounds__(256) void mlp1_kernel(
        const unsigned short* __restrict__ A,    // o bf16
        const unsigned short* __restrict__ Bt,   // W1T bf16
        const float* __restrict__ bias,          // b1
        float*       __restrict__ C)             // h [1024][512]
{
    __shared__ unsigned short As[64][72];
    __shared__ unsigned short Bs[64][72];

    const int t  = threadIdx.x;
    const int m0 = blockIdx.y * 64;
    const int n0 = blockIdx.x * 64;
    const int w  = t >> 6, l = t & 63;
    const int wr = w >> 1, wc = w & 1;          // 2x2 wave grid
    const int lr = l & 31;                      // fragment row/col
    const int lk = (l >> 5) * 8;                // fragment k offset
    const int sr = t >> 3;                      // staging row 0..31
    const int sk = (t & 7) * 8;                 // staging k offset

    f32x16 acc = {0.f,0.f,0.f,0.f,0.f,0.f,0.f,0.f,
                  0.f,0.f,0.f,0.f,0.f,0.f,0.f,0.f};

    for (int k0 = 0; k0 < K3H; k0 += 64) {
        __syncthreads();
        ushort8x ga0 = *(const ushort8x*)&A [(size_t)(m0 + sr     ) * K3H + k0 + sk];
        ushort8x ga1 = *(const ushort8x*)&A [(size_t)(m0 + sr + 32) * K3H + k0 + sk];
        ushort8x gb0 = *(const ushort8x*)&Bt[(size_t)(n0 + sr     ) * K3H + k0 + sk];
        ushort8x gb1 = *(const ushort8x*)&Bt[(size_t)(n0 + sr + 32) * K3H + k0 + sk];
        *(ushort8x*)&As[sr     ][sk] = ga0;
        *(ushort8x*)&As[sr + 32][sk] = ga1;
        *(ushort8x*)&Bs[sr     ][sk] = gb0;
        *(ushort8x*)&Bs[sr + 32][sk] = gb1;
        __syncthreads();

        #pragma unroll
        for (int kk = 0; kk < 64; kk += 16) {
            bf16x8 af = *(const bf16x8*)&As[wr * 32 + lr][kk + lk];
            bf16x8 bf = *(const bf16x8*)&Bs[wc * 32 + lr][kk + lk];
            acc = __builtin_amdgcn_mfma_f32_32x32x16_bf16(af, bf, acc, 0, 0, 0);
        }
    }

    const int col = n0 + wc * 32 + lr;
    const float bv = bias[col];
    #pragma unroll
    for (int r = 0; r < 16; ++r) {
        int row = (r & 3) + 8 * (r >> 2) + 4 * (l >> 5);
        float v = acc[r] + bv;
        C[(size_t)(m0 + wr * 32 + row) * HID + col] = fmaxf(v, 0.f);
    }
}

// ---------------------------------------------------------------------------
// Kernel 4: out = h @ W2 + b2   [1024,512] x [512,3] -> [1024,3]
// ---------------------------------------------------------------------------
__global__ __launch_bounds__(64) void mlp2_kernel(
        const float* __restrict__ h,
        const float* __restrict__ W2,
        const float* __restrict__ b2,
        float*       __restrict__ out)
{
    const int b = blockIdx.x;
    const int l = threadIdx.x;
    float a0 = 0.f, a1 = 0.f, a2 = 0.f;
    for (int k = l; k < HID; k += 64) {
        float hv = h[(size_t)b * HID + k];
        a0 += hv * W2[k * 3 + 0];
        a1 += hv * W2[k * 3 + 1];
        a2 += hv * W2[k * 3 + 2];
    }
    #pragma unroll
    for (int off = 32; off > 0; off >>= 1) {
        a0 += __shfl_down(a0, off);
        a1 += __shfl_down(a1, off);
        a2 += __shfl_down(a2, off);
    }
    if (l == 0) {
        out[b * 3 + 0] = a0 + b2[0];
        out[b * 3 + 1] = a1 + b2[1];
        out[b * 3 + 2] = a2 + b2[2];
    }
}

extern "C" void kernel_launch(void* const* d_in, const int* in_sizes, int n_in,
                              void* d_out, int out_size, void* d_ws, size_t ws_size,
                              hipStream_t stream) {
    const float* emb = (const float*)d_in[0];
    const int*   men = (const int*)  d_in[1];
    const float* W1  = (const float*)d_in[2];
    const float* b1  = (const float*)d_in[3];
    const float* W2  = (const float*)d_in[4];
    const float* b2  = (const float*)d_in[5];
    float* out = (float*)d_out;

    // ws layout (bytes):
    //   o_bf16 : 1024*2304*2 = 4718592
    //   W1T    :  512*2304*2 = 2359296
    //   h_f32  : 1024* 512*4 = 2097152
    unsigned short* o_bf = (unsigned short*)d_ws;
    unsigned short* w1t  = o_bf + (size_t)B_SZ * K3H;
    float*          h    = (float*)(w1t + (size_t)HID * K3H);

    transpose_kernel<<<dim3(K3H / 32, HID / 32), 256, 0, stream>>>(W1, w1t);
    pool_kernel<<<B_SZ, 192, 0, stream>>>(emb, men, o_bf);
    mlp1_kernel<<<dim3(HID / 64, B_SZ / 64), 256, 0, stream>>>(o_bf, w1t, b1, h);
    mlp2_kernel<<<B_SZ, 64, 0, stream>>>(h, W2, b2, out);
}

// Round 3
// 214.954 us; speedup vs baseline: 1.8348x; 1.0164x over previous
//
#include <hip/hip_runtime.h>
#include <hip/hip_bf16.h>

#define B_SZ 1024
#define S_SZ 512
#define H_SZ 768
#define K3H  2304   // 3*H
#define HID  512
#define NC   3

typedef __attribute__((ext_vector_type(8)))  __bf16        bf16x8;
typedef __attribute__((ext_vector_type(16))) float         f32x16;
typedef __attribute__((ext_vector_type(8)))  unsigned short ushort8x;

__device__ __forceinline__ unsigned short f2bf(float f) {
    unsigned u = __builtin_bit_cast(unsigned, f);
    unsigned r = (u + 0x7fffu + ((u >> 16) & 1u)) >> 16;
    return (unsigned short)r;
}

// ---------------------------------------------------------------------------
// Kernel 1: three masked-mean pools -> o[b, 3H] as bf16 (concat: label 2,3,4)
// One block per batch row, 192 threads (thread t owns float4 column t).
// Wave 0 compacts the ~60% of rows with label in {2,3,4} into an LDS list
// (deterministic ballot/prefix-popcount); label-0/1 rows never fetched.
// ---------------------------------------------------------------------------
__global__ __launch_bounds__(192) void pool_kernel(
        const float* __restrict__ emb,          // [B,S,H] f32
        const int*   __restrict__ men,          // [B,S]
        unsigned short* __restrict__ o)         // [B,3H] bf16
{
    const int b = blockIdx.x;
    const int t = threadIdx.x;

    __shared__ unsigned short sel[S_SZ];        // s | (tag<<12)
    __shared__ int nsel_sh;
    __shared__ int cnt[3];

    if (t < 64) {
        int basep = 0;
        int c0 = 0, c1 = 0, c2 = 0;
        #pragma unroll
        for (int ch = 0; ch < 8; ++ch) {
            int s = ch * 64 + t;
            int m = men[(size_t)b * S_SZ + s];
            bool pick = (m >= 2);
            unsigned long long mk = __ballot(pick);
            int pos = basep + __popcll(mk & ((1ull << t) - 1ull));
            if (pick) sel[pos] = (unsigned short)(s | ((m - 2) << 12));
            basep += __popcll(mk);
            c0 += (m == 2);
            c1 += (m == 3);
            c2 += (m == 4);
        }
        #pragma unroll
        for (int off = 32; off > 0; off >>= 1) {
            c0 += __shfl_down(c0, off);
            c1 += __shfl_down(c1, off);
            c2 += __shfl_down(c2, off);
        }
        if (t == 0) { nsel_sh = basep; cnt[0] = c0; cnt[1] = c1; cnt[2] = c2; }
    }
    __syncthreads();

    const int ns = nsel_sh;
    float4 a0 = {0.f,0.f,0.f,0.f}, a1 = {0.f,0.f,0.f,0.f}, a2 = {0.f,0.f,0.f,0.f};
    const float4* base =
        reinterpret_cast<const float4*>(emb + (size_t)b * S_SZ * H_SZ);

    #define ACCUM(E, V) do {                                             \
        int tg_ = (E) >> 12;                                             \
        if (tg_ == 0)      { a0.x+=V.x; a0.y+=V.y; a0.z+=V.z; a0.w+=V.w; } \
        else if (tg_ == 1) { a1.x+=V.x; a1.y+=V.y; a1.z+=V.z; a1.w+=V.w; } \
        else               { a2.x+=V.x; a2.y+=V.y; a2.z+=V.z; a2.w+=V.w; } \
    } while (0)

    int i = 0;
    for (; i + 4 <= ns; i += 4) {
        int e0 = sel[i], e1 = sel[i+1], e2 = sel[i+2], e3 = sel[i+3];
        float4 v0 = base[(e0 & 0x1ff) * 192 + t];
        float4 v1 = base[(e1 & 0x1ff) * 192 + t];
        float4 v2 = base[(e2 & 0x1ff) * 192 + t];
        float4 v3 = base[(e3 & 0x1ff) * 192 + t];
        ACCUM(e0, v0); ACCUM(e1, v1); ACCUM(e2, v2); ACCUM(e3, v3);
    }
    for (; i < ns; ++i) {
        int e = sel[i];
        float4 v = base[(e & 0x1ff) * 192 + t];
        ACCUM(e, v);
    }
    #undef ACCUM

    const float r0 = 1.f / (float)cnt[0];
    const float r1 = 1.f / (float)cnt[1];
    const float r2 = 1.f / (float)cnt[2];

    unsigned short* op = o + (size_t)b * K3H;
    ushort4 w0 = { f2bf(a0.x*r0), f2bf(a0.y*r0), f2bf(a0.z*r0), f2bf(a0.w*r0) };
    ushort4 w1 = { f2bf(a1.x*r1), f2bf(a1.y*r1), f2bf(a1.z*r1), f2bf(a1.w*r1) };
    ushort4 w2 = { f2bf(a2.x*r2), f2bf(a2.y*r2), f2bf(a2.z*r2), f2bf(a2.w*r2) };
    *reinterpret_cast<ushort4*>(op + 0 * H_SZ + t * 4) = w0;
    *reinterpret_cast<ushort4*>(op + 1 * H_SZ + t * 4) = w1;
    *reinterpret_cast<ushort4*>(op + 2 * H_SZ + t * 4) = w2;
}

// ---------------------------------------------------------------------------
// Kernel 2: W1 [2304][512] f32  ->  W1T [512][2304] bf16  (32x32 LDS tiles)
// ---------------------------------------------------------------------------
__global__ __launch_bounds__(256) void transpose_kernel(
        const float* __restrict__ W1, unsigned short* __restrict__ Bt)
{
    __shared__ unsigned short tile[32][33];
    const int kb = blockIdx.x * 32, nb = blockIdx.y * 32;
    const int c = threadIdx.x & 31, r0 = threadIdx.x >> 5;
    #pragma unroll
    for (int i = 0; i < 4; ++i) {
        int r = r0 + i * 8;
        tile[r][c] = f2bf(W1[(size_t)(kb + r) * HID + nb + c]);
    }
    __syncthreads();
    #pragma unroll
    for (int i = 0; i < 4; ++i) {
        int r = r0 + i * 8;
        Bt[(size_t)(nb + r) * K3H + kb + c] = tile[c][r];
    }
}

// ---------------------------------------------------------------------------
// Kernel 3: h = relu(o @ W1 + b1) via bf16 MFMA, f32 accumulate.
// 64x64 tile, BK=64, 4 waves (2x2 of 32x32 via mfma_f32_32x32x16_bf16).
// 2-phase double-buffered pipeline, reg-staged: issue next-tile global->reg
// loads BEFORE the MFMA phase, ds_write after the barrier (T3-min/T14).
// LDS linear [64][64] bf16, XOR-swizzled 16B slots (slot ^= row&7):
// read conflicts 8-way -> ~4-way, write 2-way (free).
// Grid (8,16) = 128 blocks; 1 block/CU -> explicit pipelining is the only
// latency hiding available.
// ---------------------------------------------------------------------------
__global__ __launch_bounds__(256) void mlp1_kernel(
        const unsigned short* __restrict__ A,    // o bf16  [1024][2304]
        const unsigned short* __restrict__ Bt,   // W1T bf16 [512][2304]
        const float* __restrict__ bias,          // b1
        float*       __restrict__ C)             // h [1024][512]
{
    __shared__ unsigned short lds[2][2][64 * 64];   // [buf][A/B][row*64+half]

    const int t  = threadIdx.x;
    const int m0 = blockIdx.y * 64;
    const int n0 = blockIdx.x * 64;
    const int w  = t >> 6, l = t & 63;
    const int wr = w >> 1, wc = w & 1;          // 2x2 wave grid
    const int lr = l & 31;                      // fragment row/col
    const int hi = l >> 5;                      // k sub-chunk 0/1
    const int sw = lr & 7;                      // row swizzle key (32|8)

    // staging: slotIdx = t + 256*i (i=0,1); row = slotIdx>>3, slot = slotIdx&7
    const int s_row0 = t >> 3;                  // rows 0..31
    const int s_row1 = 32 + (t >> 3);           // rows 32..63
    const int s_slot = t & 7;

    const unsigned short* a_p0 = A  + (size_t)(m0 + s_row0) * K3H + s_slot * 8;
    const unsigned short* a_p1 = A  + (size_t)(m0 + s_row1) * K3H + s_slot * 8;
    const unsigned short* b_p0 = Bt + (size_t)(n0 + s_row0) * K3H + s_slot * 8;
    const unsigned short* b_p1 = Bt + (size_t)(n0 + s_row1) * K3H + s_slot * 8;

    const int w_idx0 = s_row0 * 64 + ((s_slot ^ (s_row0 & 7)) * 8);
    const int w_idx1 = s_row1 * 64 + ((s_slot ^ (s_row1 & 7)) * 8);

    f32x16 acc = {0.f,0.f,0.f,0.f,0.f,0.f,0.f,0.f,
                  0.f,0.f,0.f,0.f,0.f,0.f,0.f,0.f};

    // prologue: stage tile 0 into buf 0
    ushort8x ra0 = *(const ushort8x*)(a_p0);
    ushort8x ra1 = *(const ushort8x*)(a_p1);
    ushort8x rb0 = *(const ushort8x*)(b_p0);
    ushort8x rb1 = *(const ushort8x*)(b_p1);
    *(ushort8x*)&lds[0][0][w_idx0] = ra0;
    *(ushort8x*)&lds[0][0][w_idx1] = ra1;
    *(ushort8x*)&lds[0][1][w_idx0] = rb0;
    *(ushort8x*)&lds[0][1][w_idx1] = rb1;
    __syncthreads();

    const int NT = K3H / 64;   // 36
    int cur = 0;
    const int a_frag_row = (wr * 32 + lr) * 64;
    const int b_frag_row = (wc * 32 + lr) * 64;

    for (int step = 0; step < NT; ++step) {
        // phase A: issue next-tile global loads (latency hides under MFMA)
        if (step + 1 < NT) {
            const size_t koff = (size_t)(step + 1) * 64;
            ra0 = *(const ushort8x*)(a_p0 + koff);
            ra1 = *(const ushort8x*)(a_p1 + koff);
            rb0 = *(const ushort8x*)(b_p0 + koff);
            rb1 = *(const ushort8x*)(b_p1 + koff);
        }

        // phase B: ds_read fragments + MFMA on buf[cur]
        const unsigned short* As = lds[cur][0];
        const unsigned short* Bs = lds[cur][1];
        #pragma unroll
        for (int kk = 0; kk < 64; kk += 16) {
            const int ks = (kk >> 3) + hi;      // 16B slot 0..7
            bf16x8 af = *(const bf16x8*)&As[a_frag_row + ((ks ^ sw) * 8)];
            bf16x8 bf = *(const bf16x8*)&Bs[b_frag_row + ((ks ^ sw) * 8)];
            acc = __builtin_amdgcn_mfma_f32_32x32x16_bf16(af, bf, acc, 0, 0, 0);
        }
        __syncthreads();                        // all waves done reading cur

        // phase C: write staged regs to the other buffer
        if (step + 1 < NT) {
            const int nb = cur ^ 1;
            *(ushort8x*)&lds[nb][0][w_idx0] = ra0;
            *(ushort8x*)&lds[nb][0][w_idx1] = ra1;
            *(ushort8x*)&lds[nb][1][w_idx0] = rb0;
            *(ushort8x*)&lds[nb][1][w_idx1] = rb1;
            __syncthreads();                    // writes visible before reads
            cur = nb;
        }
    }

    const int col = n0 + wc * 32 + lr;
    const float bv = bias[col];
    #pragma unroll
    for (int r = 0; r < 16; ++r) {
        int row = (r & 3) + 8 * (r >> 2) + 4 * hi;
        float v = acc[r] + bv;
        C[(size_t)(m0 + wr * 32 + row) * HID + col] = fmaxf(v, 0.f);
    }
}

// ---------------------------------------------------------------------------
// Kernel 4: out = h @ W2 + b2   [1024,512] x [512,3] -> [1024,3]
// ---------------------------------------------------------------------------
__global__ __launch_bounds__(64) void mlp2_kernel(
        const float* __restrict__ h,
        const float* __restrict__ W2,
        const float* __restrict__ b2,
        float*       __restrict__ out)
{
    const int b = blockIdx.x;
    const int l = threadIdx.x;
    float a0 = 0.f, a1 = 0.f, a2 = 0.f;
    for (int k = l; k < HID; k += 64) {
        float hv = h[(size_t)b * HID + k];
        a0 += hv * W2[k * 3 + 0];
        a1 += hv * W2[k * 3 + 1];
        a2 += hv * W2[k * 3 + 2];
    }
    #pragma unroll
    for (int off = 32; off > 0; off >>= 1) {
        a0 += __shfl_down(a0, off);
        a1 += __shfl_down(a1, off);
        a2 += __shfl_down(a2, off);
    }
    if (l == 0) {
        out[b * 3 + 0] = a0 + b2[0];
        out[b * 3 + 1] = a1 + b2[1];
        out[b * 3 + 2] = a2 + b2[2];
    }
}

extern "C" void kernel_launch(void* const* d_in, const int* in_sizes, int n_in,
                              void* d_out, int out_size, void* d_ws, size_t ws_size,
                              hipStream_t stream) {
    const float* emb = (const float*)d_in[0];
    const int*   men = (const int*)  d_in[1];
    const float* W1  = (const float*)d_in[2];
    const float* b1  = (const float*)d_in[3];
    const float* W2  = (const float*)d_in[4];
    const float* b2  = (const float*)d_in[5];
    float* out = (float*)d_out;

    // ws layout (bytes):
    //   o_bf16 : 1024*2304*2 = 4718592
    //   W1T    :  512*2304*2 = 2359296
    //   h_f32  : 1024* 512*4 = 2097152
    unsigned short* o_bf = (unsigned short*)d_ws;
    unsigned short* w1t  = o_bf + (size_t)B_SZ * K3H;
    float*          h    = (float*)(w1t + (size_t)HID * K3H);

    transpose_kernel<<<dim3(K3H / 32, HID / 32), 256, 0, stream>>>(W1, w1t);
    pool_kernel<<<B_SZ, 192, 0, stream>>>(emb, men, o_bf);
    mlp1_kernel<<<dim3(HID / 64, B_SZ / 64), 256, 0, stream>>>(o_bf, w1t, b1, h);
    mlp2_kernel<<<B_SZ, 64, 0, stream>>>(h, W2, b2, out);
}

// Round 4
// 197.773 us; speedup vs baseline: 1.9942x; 1.0869x over previous
//
#include <hip/hip_runtime.h>
#include <hip/hip_bf16.h>

#define B_SZ 1024
#define S_SZ 512
#define H_SZ 768
#define K3H  2304   // 3*H
#define HID  512
#define NC   3
#define KSPLIT_HALF 1152

typedef __attribute__((ext_vector_type(8)))  __bf16        bf16x8;
typedef __attribute__((ext_vector_type(16))) float         f32x16;
typedef __attribute__((ext_vector_type(8)))  unsigned short ushort8x;

__device__ __forceinline__ unsigned short f2bf(float f) {
    unsigned u = __builtin_bit_cast(unsigned, f);
    unsigned r = (u + 0x7fffu + ((u >> 16) & 1u)) >> 16;
    return (unsigned short)r;
}

// ---------------------------------------------------------------------------
// Kernel 1 (merged): blocks [0,1024) = masked-mean pool; blocks [1024,1312)
// = W1 f32->bf16 transpose (64x64 tiles). Transpose rides under the pool's
// memory shadow instead of a serial 3 us launch.
// ---------------------------------------------------------------------------
__global__ __launch_bounds__(192) void pool_tr_kernel(
        const float* __restrict__ emb,          // [B,S,H] f32
        const int*   __restrict__ men,          // [B,S]
        const float* __restrict__ W1,           // [2304][512] f32
        unsigned short* __restrict__ o,         // [B,3H] bf16
        unsigned short* __restrict__ Bt)        // W1T [512][2304] bf16
{
    const int t = threadIdx.x;

    if (blockIdx.x >= B_SZ) {
        // ---- transpose path: 64x64 tile, 36 k-tiles x 8 n-tiles = 288 ----
        __shared__ unsigned short tile[64][65];
        const int bt = blockIdx.x - B_SZ;
        const int kb = (bt >> 3) * 64;
        const int nb = (bt & 7) * 64;
        for (int i = t; i < 4096; i += 192) {
            int r = i >> 6, c = i & 63;
            tile[r][c] = f2bf(W1[(size_t)(kb + r) * HID + nb + c]);
        }
        __syncthreads();
        for (int i = t; i < 4096; i += 192) {
            int rr = i >> 6, cc = i & 63;
            Bt[(size_t)(nb + rr) * K3H + kb + cc] = tile[cc][rr];
        }
        return;
    }

    // ---- pool path ----
    const int b = blockIdx.x;
    __shared__ unsigned short sel[S_SZ];        // s | (tag<<12)
    __shared__ int nsel_sh;
    __shared__ int cnt[3];

    if (t < 64) {
        int basep = 0;
        int c0 = 0, c1 = 0, c2 = 0;
        #pragma unroll
        for (int ch = 0; ch < 8; ++ch) {
            int s = ch * 64 + t;
            int m = men[(size_t)b * S_SZ + s];
            bool pick = (m >= 2);
            unsigned long long mk = __ballot(pick);
            int pos = basep + __popcll(mk & ((1ull << t) - 1ull));
            if (pick) sel[pos] = (unsigned short)(s | ((m - 2) << 12));
            basep += __popcll(mk);
            c0 += (m == 2);
            c1 += (m == 3);
            c2 += (m == 4);
        }
        #pragma unroll
        for (int off = 32; off > 0; off >>= 1) {
            c0 += __shfl_down(c0, off);
            c1 += __shfl_down(c1, off);
            c2 += __shfl_down(c2, off);
        }
        if (t == 0) { nsel_sh = basep; cnt[0] = c0; cnt[1] = c1; cnt[2] = c2; }
    }
    __syncthreads();

    const int ns = nsel_sh;
    float4 a0 = {0.f,0.f,0.f,0.f}, a1 = {0.f,0.f,0.f,0.f}, a2 = {0.f,0.f,0.f,0.f};
    const float4* base =
        reinterpret_cast<const float4*>(emb + (size_t)b * S_SZ * H_SZ);

    #define ACCUM(E, V) do {                                             \
        int tg_ = (E) >> 12;                                             \
        if (tg_ == 0)      { a0.x+=V.x; a0.y+=V.y; a0.z+=V.z; a0.w+=V.w; } \
        else if (tg_ == 1) { a1.x+=V.x; a1.y+=V.y; a1.z+=V.z; a1.w+=V.w; } \
        else               { a2.x+=V.x; a2.y+=V.y; a2.z+=V.z; a2.w+=V.w; } \
    } while (0)

    int i = 0;
    for (; i + 4 <= ns; i += 4) {
        int e0 = sel[i], e1 = sel[i+1], e2 = sel[i+2], e3 = sel[i+3];
        float4 v0 = base[(e0 & 0x1ff) * 192 + t];
        float4 v1 = base[(e1 & 0x1ff) * 192 + t];
        float4 v2 = base[(e2 & 0x1ff) * 192 + t];
        float4 v3 = base[(e3 & 0x1ff) * 192 + t];
        ACCUM(e0, v0); ACCUM(e1, v1); ACCUM(e2, v2); ACCUM(e3, v3);
    }
    for (; i < ns; ++i) {
        int e = sel[i];
        float4 v = base[(e & 0x1ff) * 192 + t];
        ACCUM(e, v);
    }
    #undef ACCUM

    const float r0 = 1.f / (float)cnt[0];
    const float r1 = 1.f / (float)cnt[1];
    const float r2 = 1.f / (float)cnt[2];

    unsigned short* op = o + (size_t)b * K3H;
    ushort4 w0 = { f2bf(a0.x*r0), f2bf(a0.y*r0), f2bf(a0.z*r0), f2bf(a0.w*r0) };
    ushort4 w1 = { f2bf(a1.x*r1), f2bf(a1.y*r1), f2bf(a1.z*r1), f2bf(a1.w*r1) };
    ushort4 w2 = { f2bf(a2.x*r2), f2bf(a2.y*r2), f2bf(a2.z*r2), f2bf(a2.w*r2) };
    *reinterpret_cast<ushort4*>(op + 0 * H_SZ + t * 4) = w0;
    *reinterpret_cast<ushort4*>(op + 1 * H_SZ + t * 4) = w1;
    *reinterpret_cast<ushort4*>(op + 2 * H_SZ + t * 4) = w2;
}

// ---------------------------------------------------------------------------
// Kernel 2: partial GEMM  hp[kz] = o @ W1T  over k-slice kz (no bias/relu).
// 64x64 tile, BK=64, 4 waves (2x2 of 32x32 mfma_f32_32x32x16_bf16),
// 2-phase reg-staged double buffer, XOR-swizzled LDS (uniform bank spread).
// Grid (8, 16, 2) = 256 blocks -> every CU busy, 18 K-steps per block.
// ---------------------------------------------------------------------------
__global__ __launch_bounds__(256) void mlp1_kernel(
        const unsigned short* __restrict__ A,    // o bf16  [1024][2304]
        const unsigned short* __restrict__ Bt,   // W1T bf16 [512][2304]
        float*       __restrict__ hp)            // [2][1024][512] partials
{
    __shared__ unsigned short lds[2][2][64 * 64];   // [buf][A/B]

    const int t  = threadIdx.x;
    const int m0 = blockIdx.y * 64;
    const int n0 = blockIdx.x * 64;
    const int kz = blockIdx.z;
    const int kbase = kz * KSPLIT_HALF;

    const int w  = t >> 6, l = t & 63;
    const int wr = w >> 1, wc = w & 1;
    const int lr = l & 31;
    const int hi = l >> 5;
    const int sw = lr & 7;

    const int s_row0 = t >> 3;
    const int s_row1 = 32 + (t >> 3);
    const int s_slot = t & 7;

    const unsigned short* a_p0 = A  + (size_t)(m0 + s_row0) * K3H + kbase + s_slot * 8;
    const unsigned short* a_p1 = A  + (size_t)(m0 + s_row1) * K3H + kbase + s_slot * 8;
    const unsigned short* b_p0 = Bt + (size_t)(n0 + s_row0) * K3H + kbase + s_slot * 8;
    const unsigned short* b_p1 = Bt + (size_t)(n0 + s_row1) * K3H + kbase + s_slot * 8;

    const int w_idx0 = s_row0 * 64 + ((s_slot ^ (s_row0 & 7)) * 8);
    const int w_idx1 = s_row1 * 64 + ((s_slot ^ (s_row1 & 7)) * 8);

    f32x16 acc = {0.f,0.f,0.f,0.f,0.f,0.f,0.f,0.f,
                  0.f,0.f,0.f,0.f,0.f,0.f,0.f,0.f};

    ushort8x ra0 = *(const ushort8x*)(a_p0);
    ushort8x ra1 = *(const ushort8x*)(a_p1);
    ushort8x rb0 = *(const ushort8x*)(b_p0);
    ushort8x rb1 = *(const ushort8x*)(b_p1);
    *(ushort8x*)&lds[0][0][w_idx0] = ra0;
    *(ushort8x*)&lds[0][0][w_idx1] = ra1;
    *(ushort8x*)&lds[0][1][w_idx0] = rb0;
    *(ushort8x*)&lds[0][1][w_idx1] = rb1;
    __syncthreads();

    const int NT = KSPLIT_HALF / 64;   // 18
    int cur = 0;
    const int a_frag_row = (wr * 32 + lr) * 64;
    const int b_frag_row = (wc * 32 + lr) * 64;

    for (int step = 0; step < NT; ++step) {
        if (step + 1 < NT) {
            const size_t koff = (size_t)(step + 1) * 64;
            ra0 = *(const ushort8x*)(a_p0 + koff);
            ra1 = *(const ushort8x*)(a_p1 + koff);
            rb0 = *(const ushort8x*)(b_p0 + koff);
            rb1 = *(const ushort8x*)(b_p1 + koff);
        }

        const unsigned short* As = lds[cur][0];
        const unsigned short* Bs = lds[cur][1];
        #pragma unroll
        for (int kk = 0; kk < 64; kk += 16) {
            const int ks = (kk >> 3) + hi;
            bf16x8 af = *(const bf16x8*)&As[a_frag_row + ((ks ^ sw) * 8)];
            bf16x8 bf = *(const bf16x8*)&Bs[b_frag_row + ((ks ^ sw) * 8)];
            acc = __builtin_amdgcn_mfma_f32_32x32x16_bf16(af, bf, acc, 0, 0, 0);
        }
        __syncthreads();

        if (step + 1 < NT) {
            const int nb = cur ^ 1;
            *(ushort8x*)&lds[nb][0][w_idx0] = ra0;
            *(ushort8x*)&lds[nb][0][w_idx1] = ra1;
            *(ushort8x*)&lds[nb][1][w_idx0] = rb0;
            *(ushort8x*)&lds[nb][1][w_idx1] = rb1;
            __syncthreads();
            cur = nb;
        }
    }

    float* out = hp + (size_t)kz * B_SZ * HID;
    const int col = n0 + wc * 32 + lr;
    #pragma unroll
    for (int r = 0; r < 16; ++r) {
        int row = (r & 3) + 8 * (r >> 2) + 4 * hi;
        out[(size_t)(m0 + wr * 32 + row) * HID + col] = acc[r];
    }
}

// ---------------------------------------------------------------------------
// Kernel 3: out = relu(hp0 + hp1 + b1) @ W2 + b2.
// Grid 256 x 256 threads; wave w handles batch row blockIdx*4 + w.
// ---------------------------------------------------------------------------
__global__ __launch_bounds__(256) void mlp2_kernel(
        const float* __restrict__ hp,    // [2][1024][512]
        const float* __restrict__ b1,    // [512]
        const float* __restrict__ W2,    // [512][3]
        const float* __restrict__ b2,    // [3]
        float*       __restrict__ out)   // [1024][3]
{
    const int w = threadIdx.x >> 6;
    const int l = threadIdx.x & 63;
    const int b = blockIdx.x * 4 + w;

    const float* h0 = hp + (size_t)b * HID;
    const float* h1 = hp + (size_t)B_SZ * HID + (size_t)b * HID;

    float a0 = 0.f, a1 = 0.f, a2 = 0.f;
    #pragma unroll
    for (int kk = 0; kk < HID; kk += 64) {
        int k = kk + l;
        float hv = fmaxf(h0[k] + h1[k] + b1[k], 0.f);
        a0 += hv * W2[k * 3 + 0];
        a1 += hv * W2[k * 3 + 1];
        a2 += hv * W2[k * 3 + 2];
    }
    #pragma unroll
    for (int off = 32; off > 0; off >>= 1) {
        a0 += __shfl_down(a0, off);
        a1 += __shfl_down(a1, off);
        a2 += __shfl_down(a2, off);
    }
    if (l == 0) {
        out[b * 3 + 0] = a0 + b2[0];
        out[b * 3 + 1] = a1 + b2[1];
        out[b * 3 + 2] = a2 + b2[2];
    }
}

extern "C" void kernel_launch(void* const* d_in, const int* in_sizes, int n_in,
                              void* d_out, int out_size, void* d_ws, size_t ws_size,
                              hipStream_t stream) {
    const float* emb = (const float*)d_in[0];
    const int*   men = (const int*)  d_in[1];
    const float* W1  = (const float*)d_in[2];
    const float* b1  = (const float*)d_in[3];
    const float* W2  = (const float*)d_in[4];
    const float* b2  = (const float*)d_in[5];
    float* out = (float*)d_out;

    // ws layout:
    //   o_bf16 : 1024*2304*2 = 4718592 B
    //   W1T    :  512*2304*2 = 2359296 B
    //   hp     : 2*1024*512*4 = 4194304 B
    unsigned short* o_bf = (unsigned short*)d_ws;
    unsigned short* w1t  = o_bf + (size_t)B_SZ * K3H;
    float*          hp   = (float*)(w1t + (size_t)HID * K3H);

    pool_tr_kernel<<<B_SZ + 288, 192, 0, stream>>>(emb, men, W1, o_bf, w1t);
    mlp1_kernel<<<dim3(8, 16, 2), 256, 0, stream>>>(o_bf, w1t, hp);
    mlp2_kernel<<<256, 256, 0, stream>>>(hp, b1, W2, b2, out);
}